// Round 1
// baseline (9670.679 us; speedup 1.0000x reference)
//
#include <hip/hip_runtime.h>
#include <math.h>

#define HH 512      // hidden
#define BB 256      // batch
#define NK 128      // noise dim

__device__ __forceinline__ float lrelu(float x){ return x >= 0.f ? x : 0.2f*x; }
__device__ __forceinline__ float sigm(float x){ return 1.f/(1.f+expf(-x)); }

// block-wide sum over 256 threads (used by k_init)
__device__ __forceinline__ float blk_sum(float v, float* red){
  int t = threadIdx.x;
  red[t] = v; __syncthreads();
  #pragma unroll
  for (int s = 128; s > 0; s >>= 1){
    if (t < s) red[t] += red[t+s];
    __syncthreads();
  }
  float r = red[0]; __syncthreads();
  return r;
}

// full-wave (64 lane) sum, result in all lanes
__device__ __forceinline__ float wave_sum(float v){
  #pragma unroll
  for (int m = 32; m >= 1; m >>= 1) v += __shfl_xor(v, m, 64);
  return v;
}

// ---------------------------------------------------------------------------
// init: z0 = bn1(lrelu(z @ z2h_w^T + b)); h0 = z0; sz0 = bn2-half2(z0); prev=SOS
// grid: 512 blocks (one per hidden column), 256 threads (one per batch row)
// ---------------------------------------------------------------------------
__global__ __launch_bounds__(256) void k_init(
    const float* __restrict__ z, const float* __restrict__ w, const float* __restrict__ bz,
    const float* __restrict__ g1, const float* __restrict__ b1,
    const float* __restrict__ g2, const float* __restrict__ b2,
    float* __restrict__ h0, float* __restrict__ sz0, int* __restrict__ prev, int sos)
{
  __shared__ float red[256];
  int j = blockIdx.x, i = threadIdx.x;
  const float4* zr = (const float4*)(z + i*NK);
  const float4* wr = (const float4*)(w + j*NK);
  float acc = bz[j];
  #pragma unroll 8
  for (int k = 0; k < NK/4; k++){
    float4 a = zr[k], b = wr[k];
    acc = fmaf(a.x, b.x, acc); acc = fmaf(a.y, b.y, acc);
    acc = fmaf(a.z, b.z, acc); acc = fmaf(a.w, b.w, acc);
  }
  float t = lrelu(acc);
  float mu  = blk_sum(t, red) * (1.f/BB);
  float d   = t - mu;
  float var = blk_sum(d*d, red) * (1.f/BB);
  float z0v = g1[j] * d / sqrtf(var + 1e-5f) + b1[j];
  h0[i*HH + j] = z0v;
  float mu2  = blk_sum(z0v, red) * (1.f/BB);
  float d2   = z0v - mu2;
  float var2 = blk_sum(d2*d2, red) * (1.f/BB);
  sz0[i*HH + j] = g2[HH + j] * d2 / sqrtf(var2 + 1e-5f) + b2[HH + j];
  if (j == 0) prev[i] = sos;
}

// ---------------------------------------------------------------------------
// generic tiled GEMM (used ONCE for gz0 = sz0 @ Wz^T + b_ih)
// ---------------------------------------------------------------------------
__global__ __launch_bounds__(256) void k_mm(
    const float* __restrict__ A, int lda,
    const float* __restrict__ Bm, int ldb,
    const float* __restrict__ bias, int N,
    float* __restrict__ out, int ldc)
{
  __shared__ float sA[32][68];
  __shared__ float sB[64][68];
  int m0 = blockIdx.x*32, n0 = blockIdx.y*64;
  int tl = threadIdx.x;
  float acc[4][2] = {{0,0},{0,0},{0,0},{0,0}};
  int c1 = tl & 31, r4 = (tl >> 5) * 4;

  for (int kt = 0; kt < HH; kt += 64){
    #pragma unroll
    for (int rep = 0; rep < 2; rep++){
      int f = tl + 256*rep; int row = f >> 4; int kq = (f & 15) * 4;
      *(float4*)&sA[row][kq] = *(const float4*)&A[(m0+row)*lda + kt + kq];
    }
    #pragma unroll
    for (int rep = 0; rep < 4; rep++){
      int f = tl + 256*rep; int row = f >> 4; int kq = (f & 15) * 4;
      float4 v = make_float4(0.f,0.f,0.f,0.f);
      if (n0 + row < N) v = *(const float4*)&Bm[(n0+row)*ldb + kt + kq];
      *(float4*)&sB[row][kq] = v;
    }
    __syncthreads();
    #pragma unroll
    for (int kk = 0; kk < 64; kk += 4){
      float4 b0 = *(const float4*)&sB[c1     ][kk];
      float4 b1 = *(const float4*)&sB[c1 + 32][kk];
      #pragma unroll
      for (int r = 0; r < 4; r++){
        float4 a = *(const float4*)&sA[r4+r][kk];
        acc[r][0] = fmaf(a.x,b0.x, fmaf(a.y,b0.y, fmaf(a.z,b0.z, fmaf(a.w,b0.w, acc[r][0]))));
        acc[r][1] = fmaf(a.x,b1.x, fmaf(a.y,b1.y, fmaf(a.z,b1.z, fmaf(a.w,b1.w, acc[r][1]))));
      }
    }
    __syncthreads();
  }
  #pragma unroll
  for (int r = 0; r < 4; r++)
    #pragma unroll
    for (int j = 0; j < 2; j++){
      int v = n0 + c1 + 32*j;
      if (v < N) out[(m0+r4+r)*ldc + v] = acc[r][j] + bias[v];
    }
}

// ---------------------------------------------------------------------------
// fused per-step GRU kernel:
//   se = bn2_half1(lrelu(emb[prev]))   (stats computed in-block during staging)
//   gi = se@We^T (+gz0 precomputed), gh = h@Whh^T  -> h' (GRU cell)
//   o  = bn3(lrelu(h'))                (stats via wave reduce, block owns batch)
// decomposition: block = ALL 256 batch rows x 2 hidden cols; lane <-> row.
// A values: one per-lane b32 LDS read/k (odd-stride pad, conflict-free).
// B values: wave-uniform broadcast LDS reads (near-free).
// grid 256 blocks x 256 threads (1 block/CU).
// ---------------------------------------------------------------------------
__global__ __launch_bounds__(256) void k_gru2(
    const int*   __restrict__ prev, const float* __restrict__ emb,
    const float* __restrict__ g2,   const float* __restrict__ b2,
    const float* __restrict__ wih,  const float* __restrict__ whh,
    const float* __restrict__ hcur, const float* __restrict__ gz0,
    const float* __restrict__ bhh,
    const float* __restrict__ g3,   const float* __restrict__ b3,
    float* __restrict__ hnext, float* __restrict__ o_out)
{
  __shared__ float  sE[256*65];     // A chunk [256 rows][64 k], stride 65 (odd -> conflict-free)
  __shared__ float2 pstat[256*4];   // per-lane partial (sum,sumsq) for its 4 cols
  __shared__ float  sBW[64*12];     // B chunk [kk][ r_c0 r_c1 z_c0 z_c1 n_c0 n_c1 pad ]
  __shared__ float2 ssc[64];        // per-col (scale, shift) for bn2 on the fly
  __shared__ float2 wst[4][2];      // per-wave bn3 partials

  const int tid = threadIdx.x;
  const int w = tid >> 6, l = tid & 63;
  const int rq = l >> 4, m4 = (l & 15) * 4;
  const int c0 = blockIdx.x * 2;

  float aR0=0.f,aR1=0.f,aZ0=0.f,aZ1=0.f,aNI0=0.f,aNI1=0.f,aNH0=0.f,aNH1=0.f;

  // ---------------- phase E: K over the embedding half ----------------
  for (int kt = 0; kt < HH; kt += 64){
    float s0=0.f,s1=0.f,s2=0.f,s3=0.f,q0=0.f,q1=0.f,q2=0.f,q3=0.f;
    #pragma unroll
    for (int i = 0; i < 16; i++){
      int row = w*64 + i*4 + rq;
      int e = prev[row];
      float4 v = *(const float4*)&emb[(size_t)e*HH + kt + m4];
      float4 t; t.x=lrelu(v.x); t.y=lrelu(v.y); t.z=lrelu(v.z); t.w=lrelu(v.w);
      *(float4*)&sE[row*65 + m4] = t;
      s0+=t.x; q0+=t.x*t.x; s1+=t.y; q1+=t.y*t.y;
      s2+=t.z; q2+=t.z*t.z; s3+=t.w; q3+=t.w*t.w;
    }
    *(float4*)&pstat[tid*4]     = make_float4(s0,q0,s1,q1);
    *(float4*)&pstat[tid*4 + 2] = make_float4(s2,q2,s3,q3);
    #pragma unroll
    for (int m = w; m < 6; m += 4){
      int g = m >> 1, c = m & 1;
      int n = g*HH + c0 + c;
      sBW[l*12 + m] = wih[n*(2*HH) + kt + l];
    }
    __syncthreads();
    if (tid < 64){
      int mi = tid >> 2, sub = tid & 3;
      float S = 0.f, Q = 0.f;
      #pragma unroll
      for (int ww = 0; ww < 4; ww++)
        #pragma unroll
        for (int r2 = 0; r2 < 4; r2++){
          float2 p = pstat[(ww*64 + r2*16 + mi)*4 + sub];
          S += p.x; Q += p.y;
        }
      float mu  = S * (1.f/BB);
      float var = Q * (1.f/BB) - mu*mu;
      float sc  = g2[kt + tid] * rsqrtf(var + 1e-5f);
      ssc[tid] = make_float2(sc, b2[kt + tid] - mu*sc);
    }
    __syncthreads();
    #pragma unroll 4
    for (int kk = 0; kk < 64; kk++){
      float a = sE[tid*65 + kk];
      float2 ss = ssc[kk];
      float an = fmaf(a, ss.x, ss.y);
      float4 b4 = *(const float4*)&sBW[kk*12];
      float2 bn = *(const float2*)&sBW[kk*12 + 4];
      aR0  = fmaf(an, b4.x, aR0);  aR1  = fmaf(an, b4.y, aR1);
      aZ0  = fmaf(an, b4.z, aZ0);  aZ1  = fmaf(an, b4.w, aZ1);
      aNI0 = fmaf(an, bn.x, aNI0); aNI1 = fmaf(an, bn.y, aNI1);
    }
    __syncthreads();
  }

  // ---------------- phase H: K over hidden state ----------------
  for (int kt = 0; kt < HH; kt += 64){
    #pragma unroll
    for (int i = 0; i < 16; i++){
      int row = w*64 + i*4 + rq;
      float4 v = *(const float4*)&hcur[row*HH + kt + m4];
      *(float4*)&sE[row*65 + m4] = v;
    }
    #pragma unroll
    for (int m = w; m < 6; m += 4){
      int g = m >> 1, c = m & 1;
      int n = g*HH + c0 + c;
      sBW[l*12 + m] = whh[n*HH + kt + l];
    }
    __syncthreads();
    #pragma unroll 4
    for (int kk = 0; kk < 64; kk++){
      float a = sE[tid*65 + kk];
      float4 b4 = *(const float4*)&sBW[kk*12];
      float2 bn = *(const float2*)&sBW[kk*12 + 4];
      aR0  = fmaf(a, b4.x, aR0);  aR1  = fmaf(a, b4.y, aR1);
      aZ0  = fmaf(a, b4.z, aZ0);  aZ1  = fmaf(a, b4.w, aZ1);
      aNH0 = fmaf(a, bn.x, aNH0); aNH1 = fmaf(a, bn.y, aNH1);
    }
    __syncthreads();
  }

  // ---------------- epilogue: GRU cell + bn3(lrelu(h')) ----------------
  int row = tid;
  float t3v[2];
  #pragma unroll
  for (int c = 0; c < 2; c++){
    float aR  = c ? aR1  : aR0;
    float aZ  = c ? aZ1  : aZ0;
    float aNI = c ? aNI1 : aNI0;
    float aNH = c ? aNH1 : aNH0;
    int col = c0 + c;
    float rg = sigm(aR + bhh[col]      + gz0[row*(3*HH) + col]);
    float zg = sigm(aZ + bhh[HH + col] + gz0[row*(3*HH) + HH + col]);
    float ng = tanhf(aNI + gz0[row*(3*HH) + 2*HH + col] + rg*(aNH + bhh[2*HH + col]));
    float hv = hcur[row*HH + col];
    float hn = (1.f - zg)*ng + zg*hv;
    hnext[row*HH + col] = hn;
    t3v[c] = lrelu(hn);
  }
  float S0 = wave_sum(t3v[0]), Q0 = wave_sum(t3v[0]*t3v[0]);
  float S1 = wave_sum(t3v[1]), Q1 = wave_sum(t3v[1]*t3v[1]);
  if (l == 0){ wst[w][0] = make_float2(S0, Q0); wst[w][1] = make_float2(S1, Q1); }
  __syncthreads();
  #pragma unroll
  for (int c = 0; c < 2; c++){
    float S = 0.f, Q = 0.f;
    #pragma unroll
    for (int ww = 0; ww < 4; ww++){ float2 p = wst[ww][c]; S += p.x; Q += p.y; }
    float mu  = S * (1.f/BB);
    float var = Q * (1.f/BB) - mu*mu;
    int col = c0 + c;
    float sc = g3[col] * rsqrtf(var + 1e-5f);
    float sh = b3[col] - mu*sc;
    o_out[row*HH + col] = fmaf(t3v[c], sc, sh);
  }
}

// ---------------------------------------------------------------------------
// logits GEMM: out = (o @ h2o_w^T + b + gumbel) / T
// block = ALL 256 rows (lane <-> row) x 20 vocab cols; B via broadcast LDS.
// grid ceil(V/20) = 250 blocks x 256 threads.
// ---------------------------------------------------------------------------
__global__ __launch_bounds__(256) void k_mm2(
    const float* __restrict__ A,           // o [256][512]
    const float* __restrict__ W,           // h2o_w [V][512]
    const float* __restrict__ bias, int V,
    float* __restrict__ outp, int ldc,     // out + t*V, steps*V
    const float* __restrict__ gum, int ldg,
    const float* __restrict__ temp)
{
  __shared__ float sA[256*65];   // [row][k] stride 65
  __shared__ float sB[64*20];    // [kk][20 cols]
  const int tid = threadIdx.x;
  const int w = tid >> 6, l = tid & 63;
  const int rq = l >> 4, m4 = (l & 15)*4;
  const int c0 = blockIdx.x * 20;

  float acc[20];
  #pragma unroll
  for (int c = 0; c < 20; c++) acc[c] = 0.f;

  for (int kt = 0; kt < HH; kt += 64){
    #pragma unroll
    for (int i = 0; i < 16; i++){
      int row = w*64 + i*4 + rq;
      float4 v = *(const float4*)&A[row*HH + kt + m4];
      *(float4*)&sA[row*65 + m4] = v;
    }
    #pragma unroll
    for (int m = w; m < 20; m += 4){
      int n = c0 + m; if (n >= V) n = V - 1;
      sB[l*20 + m] = W[(size_t)n*HH + kt + l];
    }
    __syncthreads();
    #pragma unroll 2
    for (int kk = 0; kk < 64; kk++){
      float a = sA[tid*65 + kk];
      float4 B0 = *(const float4*)&sB[kk*20 + 0];
      float4 B1 = *(const float4*)&sB[kk*20 + 4];
      float4 B2 = *(const float4*)&sB[kk*20 + 8];
      float4 B3 = *(const float4*)&sB[kk*20 + 12];
      float4 B4 = *(const float4*)&sB[kk*20 + 16];
      acc[0]  = fmaf(a, B0.x, acc[0]);  acc[1]  = fmaf(a, B0.y, acc[1]);
      acc[2]  = fmaf(a, B0.z, acc[2]);  acc[3]  = fmaf(a, B0.w, acc[3]);
      acc[4]  = fmaf(a, B1.x, acc[4]);  acc[5]  = fmaf(a, B1.y, acc[5]);
      acc[6]  = fmaf(a, B1.z, acc[6]);  acc[7]  = fmaf(a, B1.w, acc[7]);
      acc[8]  = fmaf(a, B2.x, acc[8]);  acc[9]  = fmaf(a, B2.y, acc[9]);
      acc[10] = fmaf(a, B2.z, acc[10]); acc[11] = fmaf(a, B2.w, acc[11]);
      acc[12] = fmaf(a, B3.x, acc[12]); acc[13] = fmaf(a, B3.y, acc[13]);
      acc[14] = fmaf(a, B3.z, acc[14]); acc[15] = fmaf(a, B3.w, acc[15]);
      acc[16] = fmaf(a, B4.x, acc[16]); acc[17] = fmaf(a, B4.y, acc[17]);
      acc[18] = fmaf(a, B4.z, acc[18]); acc[19] = fmaf(a, B4.w, acc[19]);
    }
    __syncthreads();
  }

  float invT = 1.f / temp[0];
  int row = tid;
  float* op = outp + (size_t)row*ldc + c0;
  const float* gp = gum + (size_t)row*ldg + c0;
  if (c0 + 20 <= V){
    #pragma unroll
    for (int qd = 0; qd < 5; qd++){
      float4 u = *(const float4*)&gp[qd*4];
      float4 r;
      r.x = (acc[qd*4+0] + bias[c0+qd*4+0] - logf(-logf(u.x + 1e-20f) + 1e-20f)) * invT;
      r.y = (acc[qd*4+1] + bias[c0+qd*4+1] - logf(-logf(u.y + 1e-20f) + 1e-20f)) * invT;
      r.z = (acc[qd*4+2] + bias[c0+qd*4+2] - logf(-logf(u.z + 1e-20f) + 1e-20f)) * invT;
      r.w = (acc[qd*4+3] + bias[c0+qd*4+3] - logf(-logf(u.w + 1e-20f) + 1e-20f)) * invT;
      *(float4*)&op[qd*4] = r;
    }
  } else {
    for (int c = 0; c < 20; c++){
      int n = c0 + c; if (n >= V) break;
      float u = gp[c];
      op[c] = (acc[c] + bias[n] - logf(-logf(u + 1e-20f) + 1e-20f)) * invT;
    }
  }
}

// ---------------------------------------------------------------------------
// softmax (in place) + argmax -> prev ; grid BB blocks, 256 threads
// ---------------------------------------------------------------------------
__global__ __launch_bounds__(256) void k_softmax(
    float* __restrict__ outrow, int ldc, int V, int* __restrict__ prev)
{
  __shared__ float sbuf[5000];
  __shared__ float rmax[256];
  __shared__ int   ridx[256];
  __shared__ float rsum[256];
  int i = blockIdx.x, t = threadIdx.x;
  float* row = outrow + (long)i*ldc;
  float bm = -3.4e38f; int bi = 0;
  for (int v = t; v < V; v += 256){
    float s = row[v]; sbuf[v] = s;
    if (s > bm){ bm = s; bi = v; }
  }
  rmax[t] = bm; ridx[t] = bi; __syncthreads();
  for (int s = 128; s > 0; s >>= 1){
    if (t < s){
      float mv = rmax[t+s]; int mi = ridx[t+s];
      if (mv > rmax[t] || (mv == rmax[t] && mi < ridx[t])){ rmax[t] = mv; ridx[t] = mi; }
    }
    __syncthreads();
  }
  float m = rmax[0];
  float ls = 0.f;
  for (int v = t; v < V; v += 256){
    float p = expf(sbuf[v] - m); sbuf[v] = p; ls += p;
  }
  rsum[t] = ls; __syncthreads();
  for (int s = 128; s > 0; s >>= 1){
    if (t < s) rsum[t] += rsum[t+s];
    __syncthreads();
  }
  float inv = 1.f / rsum[0];
  for (int v = t; v < V; v += 256) row[v] = sbuf[v] * inv;
  if (t == 0) prev[i] = ridx[0];
}

// ---------------------------------------------------------------------------
extern "C" void kernel_launch(void* const* d_in, const int* in_sizes, int n_in,
                              void* d_out, int out_size, void* d_ws, size_t ws_size,
                              hipStream_t stream)
{
  const float* z     = (const float*)d_in[0];
  const float* z2h_w = (const float*)d_in[1];
  const float* z2h_b = (const float*)d_in[2];
  const float* emb   = (const float*)d_in[3];
  const float* bn1_g = (const float*)d_in[4];
  const float* bn1_b = (const float*)d_in[5];
  const float* bn2_g = (const float*)d_in[6];
  const float* bn2_b = (const float*)d_in[7];
  const float* bn3_g = (const float*)d_in[8];
  const float* bn3_b = (const float*)d_in[9];
  const float* wih   = (const float*)d_in[10];
  const float* whh   = (const float*)d_in[11];
  const float* bih   = (const float*)d_in[12];
  const float* bhh   = (const float*)d_in[13];
  const float* h2o_w = (const float*)d_in[14];
  const float* h2o_b = (const float*)d_in[15];
  const float* gum   = (const float*)d_in[16];
  const float* temp  = (const float*)d_in[18];
  float* out = (float*)d_out;

  int V = in_sizes[15];                 // vocab (h2o_b)
  int steps = out_size / (BB * V);

  char* ws = (char*)d_ws;
  float* sz0 = (float*)ws;  ws += (size_t)BB*HH*4;
  float* gz0 = (float*)ws;  ws += (size_t)BB*3*HH*4;
  float* hb0 = (float*)ws;  ws += (size_t)BB*HH*4;
  float* hb1 = (float*)ws;  ws += (size_t)BB*HH*4;
  float* ob  = (float*)ws;  ws += (size_t)BB*HH*4;
  int*   prev = (int*)ws;

  k_init<<<HH, 256, 0, stream>>>(z, z2h_w, z2h_b, bn1_g, bn1_b, bn2_g, bn2_b,
                                 hb0, sz0, prev, V - 1);
  // gz0 = sz0 @ Wz^T + b_ih   (Wz = wih[:, 512:], row stride 1024)
  k_mm<<<dim3(BB/32, (3*HH)/64), 256, 0, stream>>>(
      sz0, HH, wih + HH, 2*HH, bih, 3*HH, gz0, 3*HH);

  int mmg = (V + 19) / 20;
  for (int t = 0; t < steps; t++){
    const float* hc = (t & 1) ? hb1 : hb0;
    float*       hn = (t & 1) ? hb0 : hb1;
    k_gru2<<<HH/2, 256, 0, stream>>>(prev, emb, bn2_g, bn2_b, wih, whh, hc,
                                     gz0, bhh, bn3_g, bn3_b, hn, ob);
    k_mm2<<<mmg, 256, 0, stream>>>(ob, h2o_w, h2o_b, V,
                                   out + (size_t)t*V, steps*V,
                                   gum + (size_t)t*BB*V, V, temp);
    k_softmax<<<BB, 256, 0, stream>>>(out + (size_t)t*V, steps*V, V, prev);
  }
}

// Round 2
// 5936.435 us; speedup vs baseline: 1.6290x; 1.6290x over previous
//
#include <hip/hip_runtime.h>
#include <math.h>

#define HH 512      // hidden
#define BB 256      // batch
#define NK 128      // noise dim
#define G3 1536     // 3*HH
#define N6 3072     // 6*HH (gi|gh concatenated output)

__device__ __forceinline__ float lrelu(float x){ return x >= 0.f ? x : 0.2f*x; }
__device__ __forceinline__ float sigm(float x){ return 1.f/(1.f+expf(-x)); }

// block-wide sum over 256 threads
__device__ __forceinline__ float blk_sum(float v, float* red){
  int t = threadIdx.x;
  red[t] = v; __syncthreads();
  #pragma unroll
  for (int s = 128; s > 0; s >>= 1){
    if (t < s) red[t] += red[t+s];
    __syncthreads();
  }
  float r = red[0]; __syncthreads();
  return r;
}

// block-wide (sum, sumsq) over 256 threads
__device__ __forceinline__ float2 blk_sum2(float2 v, float2* red){
  int t = threadIdx.x;
  red[t] = v; __syncthreads();
  #pragma unroll
  for (int s = 128; s > 0; s >>= 1){
    if (t < s){ red[t].x += red[t+s].x; red[t].y += red[t+s].y; }
    __syncthreads();
  }
  float2 r = red[0]; __syncthreads();
  return r;
}

// ---------------------------------------------------------------------------
// init: z0 = bn1(lrelu(z @ z2h_w^T + b)); h0T[col][i] = z0; sz0[i][k] = bn2-half2(z0)
// grid 512 (col), 256 thr (i)
// ---------------------------------------------------------------------------
__global__ __launch_bounds__(256) void k_init(
    const float* __restrict__ z, const float* __restrict__ w, const float* __restrict__ bz,
    const float* __restrict__ g1, const float* __restrict__ b1,
    const float* __restrict__ g2, const float* __restrict__ b2,
    float* __restrict__ h0T, float* __restrict__ sz0, int* __restrict__ prev, int sos)
{
  __shared__ float red[256];
  int j = blockIdx.x, i = threadIdx.x;
  const float4* zr = (const float4*)(z + i*NK);
  const float4* wr = (const float4*)(w + j*NK);
  float acc = bz[j];
  #pragma unroll 8
  for (int k = 0; k < NK/4; k++){
    float4 a = zr[k], b = wr[k];
    acc = fmaf(a.x, b.x, acc); acc = fmaf(a.y, b.y, acc);
    acc = fmaf(a.z, b.z, acc); acc = fmaf(a.w, b.w, acc);
  }
  float t = lrelu(acc);
  float mu  = blk_sum(t, red) * (1.f/BB);
  float d   = t - mu;
  float var = blk_sum(d*d, red) * (1.f/BB);
  float z0v = g1[j] * d / sqrtf(var + 1e-5f) + b1[j];
  h0T[j*BB + i] = z0v;                       // transposed [col][i]
  float mu2  = blk_sum(z0v, red) * (1.f/BB);
  float d2   = z0v - mu2;
  float var2 = blk_sum(d2*d2, red) * (1.f/BB);
  sz0[i*HH + j] = g2[HH + j] * d2 / sqrtf(var2 + 1e-5f) + b2[HH + j];
  if (j == 0) prev[i] = sos;
}

// ---------------------------------------------------------------------------
// generic tiled GEMM, used ONCE at init: gz0 = sz0 @ Wz^T + b_ih
// ---------------------------------------------------------------------------
__global__ __launch_bounds__(256) void k_mm(
    const float* __restrict__ A, int lda,
    const float* __restrict__ Bm, int ldb,
    const float* __restrict__ bias, int N,
    float* __restrict__ out, int ldc)
{
  __shared__ float sA[32][68];
  __shared__ float sB[64][68];
  int m0 = blockIdx.x*32, n0 = blockIdx.y*64;
  int tl = threadIdx.x;
  float acc[4][2] = {{0,0},{0,0},{0,0},{0,0}};
  int c1 = tl & 31, r4 = (tl >> 5) * 4;

  for (int kt = 0; kt < HH; kt += 64){
    #pragma unroll
    for (int rep = 0; rep < 2; rep++){
      int f = tl + 256*rep; int row = f >> 4; int kq = (f & 15) * 4;
      *(float4*)&sA[row][kq] = *(const float4*)&A[(m0+row)*lda + kt + kq];
    }
    #pragma unroll
    for (int rep = 0; rep < 4; rep++){
      int f = tl + 256*rep; int row = f >> 4; int kq = (f & 15) * 4;
      float4 v = make_float4(0.f,0.f,0.f,0.f);
      if (n0 + row < N) v = *(const float4*)&Bm[(n0+row)*ldb + kt + kq];
      *(float4*)&sB[row][kq] = v;
    }
    __syncthreads();
    #pragma unroll
    for (int kk = 0; kk < 64; kk += 4){
      float4 b0 = *(const float4*)&sB[c1     ][kk];
      float4 b1 = *(const float4*)&sB[c1 + 32][kk];
      #pragma unroll
      for (int r = 0; r < 4; r++){
        float4 a = *(const float4*)&sA[r4+r][kk];
        acc[r][0] = fmaf(a.x,b0.x, fmaf(a.y,b0.y, fmaf(a.z,b0.z, fmaf(a.w,b0.w, acc[r][0]))));
        acc[r][1] = fmaf(a.x,b1.x, fmaf(a.y,b1.y, fmaf(a.z,b1.z, fmaf(a.w,b1.w, acc[r][1]))));
      }
    }
    __syncthreads();
  }
  #pragma unroll
  for (int r = 0; r < 4; r++)
    #pragma unroll
    for (int j = 0; j < 2; j++){
      int v = n0 + c1 + 32*j;
      if (v < N) out[(m0+r4+r)*ldc + v] = acc[r][j] + bias[v];
    }
}

// ---------------------------------------------------------------------------
// per-step: seT[col][i] = bn2_half1(lrelu(emb[prev[i]][col]))
// grid 512 (col), 256 thr (i)
// ---------------------------------------------------------------------------
__global__ __launch_bounds__(256) void k_embed2(
    const int* __restrict__ prev, const float* __restrict__ emb,
    const float* __restrict__ g2, const float* __restrict__ b2,
    float* __restrict__ seT)
{
  __shared__ float2 red[256];
  int col = blockIdx.x, i = threadIdx.x;
  float t = lrelu(emb[(size_t)prev[i]*HH + col]);
  float2 sq = blk_sum2(make_float2(t, t*t), red);
  float mu  = sq.x * (1.f/BB);
  float var = sq.y * (1.f/BB) - mu*mu;
  float sc  = g2[col] * rsqrtf(var + 1e-5f);
  seT[col*BB + i] = fmaf(t, sc, b2[col] - mu*sc);
}

// ---------------------------------------------------------------------------
// GRU GEMM partials: C[256][3072] = [se|h] @ [We;Whh]^T, K-split.
// n in [0,1536): gi (A=seT, B=wih cols 0..511); n in [1536,3072): gh (A=hT, B=whh)
// block 128x128, BK=16, thread tile 8x8. grid (2, 24, KS). output transposed:
// gAllT[ks][n][i]
// ---------------------------------------------------------------------------
__global__ __launch_bounds__(256) void k_gru3(
    const float* __restrict__ seT, const float* __restrict__ hT,
    const float* __restrict__ wih, const float* __restrict__ whh,
    float* __restrict__ gAllT, int Kb)
{
  __shared__ float sA[16][132];
  __shared__ float sB[16][132];
  const int tid = threadIdx.x;
  const int rt = tid & 15, ct = tid >> 4;
  const int m0 = blockIdx.x * 128;
  const int n0 = blockIdx.y * 128;
  const int k0 = blockIdx.z * Kb;
  const bool hi = (n0 >= G3);
  const float* __restrict__ XT = hi ? hT : seT;

  float acc[8][8];
  #pragma unroll
  for (int r = 0; r < 8; r++)
    #pragma unroll
    for (int c = 0; c < 8; c++) acc[r][c] = 0.f;

  const int am4 = (tid & 31) * 4, akk = tid >> 5;    // A stage: 32 m-chunks x 8 kk
  const int bn  = tid & 127,     bkq = (tid >> 7)*4; // B stage: 128 n x 2 kq

  const int nkt = Kb >> 4;
  for (int kt = 0; kt < nkt; kt++){
    int kb = k0 + kt*16;
    // stage A (direct copy, [k][m] <- XT[k][m])
    #pragma unroll
    for (int p = 0; p < 2; p++){
      int kk = akk + p*8;
      *(float4*)&sA[kk][am4] = *(const float4*)&XT[(size_t)(kb + kk)*BB + m0 + am4];
    }
    // stage B (transpose, [k][n] <- W[n][k])
    {
      int n = n0 + bn;
      const float* Wr = hi ? (whh + (size_t)(n - G3)*HH) : (wih + (size_t)n*1024);
      #pragma unroll
      for (int p = 0; p < 2; p++){
        int kq = bkq + p*8;
        float4 v = *(const float4*)&Wr[kb + kq];
        sB[kq+0][bn] = v.x; sB[kq+1][bn] = v.y;
        sB[kq+2][bn] = v.z; sB[kq+3][bn] = v.w;
      }
    }
    __syncthreads();
    #pragma unroll
    for (int kk = 0; kk < 16; kk++){
      float4 a0 = *(const float4*)&sA[kk][rt*8];
      float4 a1 = *(const float4*)&sA[kk][rt*8 + 4];
      float4 b0 = *(const float4*)&sB[kk][ct*8];
      float4 b1 = *(const float4*)&sB[kk][ct*8 + 4];
      float av[8] = {a0.x,a0.y,a0.z,a0.w,a1.x,a1.y,a1.z,a1.w};
      float bv[8] = {b0.x,b0.y,b0.z,b0.w,b1.x,b1.y,b1.z,b1.w};
      #pragma unroll
      for (int r = 0; r < 8; r++)
        #pragma unroll
        for (int c = 0; c < 8; c++)
          acc[r][c] = fmaf(av[r], bv[c], acc[r][c]);
    }
    __syncthreads();
  }

  // write transposed partials: gAllT[bz][n][i], float4 along i
  float* base = gAllT + (size_t)blockIdx.z * N6 * BB;
  #pragma unroll
  for (int c = 0; c < 8; c++){
    int n = n0 + ct*8 + c;
    float* dst = base + (size_t)n*BB + m0 + rt*8;
    *(float4*)&dst[0] = make_float4(acc[0][c], acc[1][c], acc[2][c], acc[3][c]);
    *(float4*)&dst[4] = make_float4(acc[4][c], acc[5][c], acc[6][c], acc[7][c]);
  }
}

// ---------------------------------------------------------------------------
// GRU cell + bn3, fused with K-split reduction.
// grid 512 (col), 256 thr (i). reads gAllT[ks][n][i] coalesced.
// ---------------------------------------------------------------------------
__global__ __launch_bounds__(256) void k_cell(
    const float* __restrict__ gAllT, int KS,
    const float* __restrict__ gz0, const float* __restrict__ bhh,
    const float* __restrict__ hcT,
    const float* __restrict__ g3, const float* __restrict__ b3,
    float* __restrict__ hnT, float* __restrict__ oT)
{
  __shared__ float2 red[256];
  int col = blockIdx.x, i = threadIdx.x;
  float giR=0.f, giZ=0.f, giN=0.f, ghR=0.f, ghZ=0.f, ghN=0.f;
  for (int ks = 0; ks < KS; ks++){
    const float* b = gAllT + (size_t)ks * N6 * BB;
    giR += b[(size_t)(       col)*BB + i];
    giZ += b[(size_t)( HH  + col)*BB + i];
    giN += b[(size_t)(2*HH + col)*BB + i];
    ghR += b[(size_t)(G3       + col)*BB + i];
    ghZ += b[(size_t)(G3 +  HH + col)*BB + i];
    ghN += b[(size_t)(G3 + 2*HH + col)*BB + i];
  }
  const float* gz = gz0 + (size_t)i*G3;
  float rg = sigm(giR + gz[col]        + ghR + bhh[col]);
  float zg = sigm(giZ + gz[HH + col]   + ghZ + bhh[HH + col]);
  float ng = tanhf(giN + gz[2*HH + col] + rg*(ghN + bhh[2*HH + col]));
  float hv = hcT[col*BB + i];
  float hn = (1.f - zg)*ng + zg*hv;
  hnT[col*BB + i] = hn;
  float t3 = lrelu(hn);
  float2 sq = blk_sum2(make_float2(t3, t3*t3), red);
  float mu  = sq.x * (1.f/BB);
  float var = sq.y * (1.f/BB) - mu*mu;
  float sc  = g3[col] * rsqrtf(var + 1e-5f);
  oT[col*BB + i] = fmaf(t3, sc, b3[col] - mu*sc);
}

// ---------------------------------------------------------------------------
// logits GEMM partials: pm[ks][i][V] = (o @ h2o_w^T) K-slice.
// block 128x128, BK=16, thread tile 8x8. grid (2, ceil(V/128), KS).
// ---------------------------------------------------------------------------
__global__ __launch_bounds__(256) void k_mm3(
    const float* __restrict__ oT, const float* __restrict__ W, int V,
    float* __restrict__ pm, int Kb)
{
  __shared__ float sA[16][132];
  __shared__ float sB[16][132];
  const int tid = threadIdx.x;
  const int rt = tid & 15, ct = tid >> 4;
  const int m0 = blockIdx.x * 128;
  const int n0 = blockIdx.y * 128;
  const int k0 = blockIdx.z * Kb;

  float acc[8][8];
  #pragma unroll
  for (int r = 0; r < 8; r++)
    #pragma unroll
    for (int c = 0; c < 8; c++) acc[r][c] = 0.f;

  const int am4 = (tid & 31) * 4, akk = tid >> 5;
  const int bn  = tid & 127,     bkq = (tid >> 7)*4;
  int nrow = n0 + bn; if (nrow >= V) nrow = V - 1;
  const float* Wr = W + (size_t)nrow*HH;

  const int nkt = Kb >> 4;
  for (int kt = 0; kt < nkt; kt++){
    int kb = k0 + kt*16;
    #pragma unroll
    for (int p = 0; p < 2; p++){
      int kk = akk + p*8;
      *(float4*)&sA[kk][am4] = *(const float4*)&oT[(size_t)(kb + kk)*BB + m0 + am4];
    }
    #pragma unroll
    for (int p = 0; p < 2; p++){
      int kq = bkq + p*8;
      float4 v = *(const float4*)&Wr[kb + kq];
      sB[kq+0][bn] = v.x; sB[kq+1][bn] = v.y;
      sB[kq+2][bn] = v.z; sB[kq+3][bn] = v.w;
    }
    __syncthreads();
    #pragma unroll
    for (int kk = 0; kk < 16; kk++){
      float4 a0 = *(const float4*)&sA[kk][rt*8];
      float4 a1 = *(const float4*)&sA[kk][rt*8 + 4];
      float4 b0 = *(const float4*)&sB[kk][ct*8];
      float4 b1 = *(const float4*)&sB[kk][ct*8 + 4];
      float av[8] = {a0.x,a0.y,a0.z,a0.w,a1.x,a1.y,a1.z,a1.w};
      float bv[8] = {b0.x,b0.y,b0.z,b0.w,b1.x,b1.y,b1.z,b1.w};
      #pragma unroll
      for (int r = 0; r < 8; r++)
        #pragma unroll
        for (int c = 0; c < 8; c++)
          acc[r][c] = fmaf(av[r], bv[c], acc[r][c]);
    }
    __syncthreads();
  }

  float* base = pm + (size_t)blockIdx.z * BB * V;
  #pragma unroll
  for (int r = 0; r < 8; r++){
    int i = m0 + rt*8 + r;
    float* dst = base + (size_t)i*V;
    #pragma unroll
    for (int g = 0; g < 2; g++){
      int v4 = n0 + ct*8 + g*4;
      if (v4 < V)
        *(float4*)&dst[v4] = make_float4(acc[r][g*4], acc[r][g*4+1], acc[r][g*4+2], acc[r][g*4+3]);
    }
  }
}

// ---------------------------------------------------------------------------
// softmax: sum K-split partials + bias + gumbel, /T, softmax, argmax -> prev
// grid BB (row i), 256 thr
// ---------------------------------------------------------------------------
__global__ __launch_bounds__(256) void k_softmax2(
    const float* __restrict__ pm, int KS,
    const float* __restrict__ bias,
    const float* __restrict__ gum, const float* __restrict__ temp,
    float* __restrict__ outrow, int ldc, int V, int* __restrict__ prev)
{
  __shared__ float sbuf[5000];
  __shared__ float rmax[256];
  __shared__ int   ridx[256];
  __shared__ float rsum[256];
  int i = blockIdx.x, t = threadIdx.x;
  float invT = 1.f / temp[0];
  const float* gp = gum + (size_t)i*V;
  float bm = -3.4e38f; int bi = 0;
  for (int v = 4*t; v < V; v += 1024){
    float4 zz = make_float4(0.f,0.f,0.f,0.f);
    for (int ks = 0; ks < KS; ks++){
      float4 p = *(const float4*)&pm[((size_t)ks*BB + i)*V + v];
      zz.x += p.x; zz.y += p.y; zz.z += p.z; zz.w += p.w;
    }
    float4 bv = *(const float4*)&bias[v];
    float4 u  = *(const float4*)&gp[v];
    zz.x = (zz.x + bv.x - logf(-logf(u.x + 1e-20f) + 1e-20f)) * invT;
    zz.y = (zz.y + bv.y - logf(-logf(u.y + 1e-20f) + 1e-20f)) * invT;
    zz.z = (zz.z + bv.z - logf(-logf(u.z + 1e-20f) + 1e-20f)) * invT;
    zz.w = (zz.w + bv.w - logf(-logf(u.w + 1e-20f) + 1e-20f)) * invT;
    *(float4*)&sbuf[v] = zz;
    if (zz.x > bm){ bm = zz.x; bi = v;   }
    if (zz.y > bm){ bm = zz.y; bi = v+1; }
    if (zz.z > bm){ bm = zz.z; bi = v+2; }
    if (zz.w > bm){ bm = zz.w; bi = v+3; }
  }
  rmax[t] = bm; ridx[t] = bi; __syncthreads();
  for (int s = 128; s > 0; s >>= 1){
    if (t < s){
      float mv = rmax[t+s]; int mi = ridx[t+s];
      if (mv > rmax[t] || (mv == rmax[t] && mi < ridx[t])){ rmax[t] = mv; ridx[t] = mi; }
    }
    __syncthreads();
  }
  float m = rmax[0];
  float ls = 0.f;
  for (int v = 4*t; v < V; v += 1024){
    float4 zz = *(const float4*)&sbuf[v];
    zz.x = expf(zz.x - m); zz.y = expf(zz.y - m);
    zz.z = expf(zz.z - m); zz.w = expf(zz.w - m);
    *(float4*)&sbuf[v] = zz;
    ls += zz.x + zz.y + zz.z + zz.w;
  }
  rsum[t] = ls; __syncthreads();
  for (int s = 128; s > 0; s >>= 1){
    if (t < s) rsum[t] += rsum[t+s];
    __syncthreads();
  }
  float inv = 1.f / rsum[0];
  float* row = outrow + (size_t)i*ldc;
  for (int v = 4*t; v < V; v += 1024){
    float4 zz = *(const float4*)&sbuf[v];
    zz.x *= inv; zz.y *= inv; zz.z *= inv; zz.w *= inv;
    *(float4*)&row[v] = zz;
  }
  if (t == 0) prev[i] = ridx[0];
}

// ---------------------------------------------------------------------------
extern "C" void kernel_launch(void* const* d_in, const int* in_sizes, int n_in,
                              void* d_out, int out_size, void* d_ws, size_t ws_size,
                              hipStream_t stream)
{
  const float* z     = (const float*)d_in[0];
  const float* z2h_w = (const float*)d_in[1];
  const float* z2h_b = (const float*)d_in[2];
  const float* emb   = (const float*)d_in[3];
  const float* bn1_g = (const float*)d_in[4];
  const float* bn1_b = (const float*)d_in[5];
  const float* bn2_g = (const float*)d_in[6];
  const float* bn2_b = (const float*)d_in[7];
  const float* bn3_g = (const float*)d_in[8];
  const float* bn3_b = (const float*)d_in[9];
  const float* wih   = (const float*)d_in[10];
  const float* whh   = (const float*)d_in[11];
  const float* bih   = (const float*)d_in[12];
  const float* bhh   = (const float*)d_in[13];
  const float* h2o_w = (const float*)d_in[14];
  const float* h2o_b = (const float*)d_in[15];
  const float* gum   = (const float*)d_in[16];
  const float* temp  = (const float*)d_in[18];
  float* out = (float*)d_out;

  int V = in_sizes[15];                 // vocab (h2o_b length)
  int steps = out_size / (BB * V);

  // workspace budget: pick K-split factors that fit
  size_t fixed = (size_t)BB*HH*4      // sz0
               + (size_t)BB*G3*4      // gz0
               + (size_t)HH*BB*4*4    // seT, hT0, hT1, oT
               + 1024;                // prev
  int cand[4][2] = {{8,4},{4,2},{2,1},{1,1}};
  int ksg = 1, ksm = 1;
  for (int c = 0; c < 4; c++){
    size_t need = fixed + (size_t)cand[c][0]*N6*BB*4 + (size_t)cand[c][1]*BB*V*4;
    if (need <= ws_size){ ksg = cand[c][0]; ksm = cand[c][1]; break; }
  }

  char* ws = (char*)d_ws;
  float* sz0 = (float*)ws;  ws += (size_t)BB*HH*4;
  float* gz0 = (float*)ws;  ws += (size_t)BB*G3*4;
  float* seT = (float*)ws;  ws += (size_t)HH*BB*4;
  float* hT0 = (float*)ws;  ws += (size_t)HH*BB*4;
  float* hT1 = (float*)ws;  ws += (size_t)HH*BB*4;
  float* oT  = (float*)ws;  ws += (size_t)HH*BB*4;
  float* gAllT = (float*)ws; ws += (size_t)ksg*N6*BB*4;
  float* pm  = (float*)ws;  ws += (size_t)ksm*BB*V*4;
  int*   prev = (int*)ws;

  k_init<<<HH, 256, 0, stream>>>(z, z2h_w, z2h_b, bn1_g, bn1_b, bn2_g, bn2_b,
                                 hT0, sz0, prev, V - 1);
  // gz0 = sz0 @ Wz^T + b_ih   (Wz = wih[:, 512:], row stride 1024)
  k_mm<<<dim3(BB/32, G3/64), 256, 0, stream>>>(
      sz0, HH, wih + HH, 2*HH, bih, G3, gz0, G3);

  int Kb_g = HH / ksg;
  int Kb_m = HH / ksm;
  int nb_v = (V + 127) / 128;

  for (int t = 0; t < steps; t++){
    const float* hc = (t & 1) ? hT1 : hT0;
    float*       hn = (t & 1) ? hT0 : hT1;
    k_embed2<<<HH, 256, 0, stream>>>(prev, emb, bn2_g, bn2_b, seT);
    k_gru3<<<dim3(2, N6/128, ksg), 256, 0, stream>>>(seT, hc, wih, whh, gAllT, Kb_g);
    k_cell<<<HH, 256, 0, stream>>>(gAllT, ksg, gz0, bhh, hc, bn3_g, bn3_b, hn, oT);
    k_mm3<<<dim3(2, nb_v, ksm), 256, 0, stream>>>(oT, h2o_w, V, pm, Kb_m);
    k_softmax2<<<BB, 256, 0, stream>>>(pm, ksm, h2o_b,
                                       gum + (size_t)t*BB*V, temp,
                                       out + (size_t)t*V, steps*V, V, prev);
  }
}